// Round 1
// baseline (5803.963 us; speedup 1.0000x reference)
//
#include <hip/hip_runtime.h>
#include <math.h>

// ---------------- problem constants ----------------
// B=64, P=14*14=196, H=E=A=512, V=10000, T=49 (MAXCAP-1), gates=2048, Kx=1536

// ---------------- ws layout (float/int element offsets) ----------------
#define WS_SORT 0               // int[64]
#define WS_DL   64              // int[64]
#define WS_NB   128             // int[64] (49 used)
#define WS_CAPS 192             // int[64*50]
#define WS_H    3392            // float[64*512]
#define WS_C    36160           // float[64*512]
#define WS_CTX  68928           // float[64*512]
#define WS_P2   101696          // float[16][64][512]  att2 k-split partials
#define WS_PG   625984          // float[16][64][2048] gates k-split partials
#define WS_PSC  2723136         // float[4][64][10048] score k-split partials
#define WS_ENC  5295424         // float[12544*512] enc_att
// end = 11,717,952 floats = 46.9 MB

// ---------------- out layout (floats) ----------------
#define OUT_SCORES 0            // (64,49,10000)
#define OUT_CAPS   31360000     // (64,50)
#define OUT_DL     31363200     // (64,)
#define OUT_W      31363264     // (64,49,196)
#define OUT_SORT   31977920     // (64,)

#define KC  32                  // GEMM K-chunk
#define LST 68                  // LDS row stride (pad: 16B-aligned, low conflict)

__device__ __forceinline__ float sigm(float x) { return 1.f / (1.f + expf(-x)); }

// ---------------- shared fp32 GEMM core: 64 threads, 64x64 tile, 8x8 micro ----------------
__device__ __forceinline__ void gemm_acc(const float* __restrict__ As, const float* __restrict__ Bs,
                                         float acc[8][8], int tx, int ty) {
#pragma unroll 8
  for (int kk = 0; kk < KC; ++kk) {
    const float4* ar = (const float4*)(As + kk * LST + tx * 8);
    const float4* br = (const float4*)(Bs + kk * LST + ty * 8);
    float4 a0 = ar[0], a1 = ar[1];
    float4 b0 = br[0], b1 = br[1];
    float av[8] = {a0.x, a0.y, a0.z, a0.w, a1.x, a1.y, a1.z, a1.w};
    float bv[8] = {b0.x, b0.y, b0.z, b0.w, b1.x, b1.y, b1.z, b1.w};
#pragma unroll
    for (int i = 0; i < 8; ++i)
#pragma unroll
      for (int j = 0; j < 8; ++j)
        acc[i][j] = fmaf(av[i], bv[j], acc[i][j]);
  }
}

// load 64 rows x 32 k from row-major src (rows row0..row0+63, leading dim ld), transpose to LDS [k][m]
__device__ __forceinline__ void load_tile_strided(const float* __restrict__ src, int row0, int ld, int k0,
                                                  float* __restrict__ dst, int tid, int nrows_valid) {
#pragma unroll
  for (int i = 0; i < 8; ++i) {
    int lin = tid + 64 * i;
    int m = lin >> 3, kf = lin & 7;
    float4 v = make_float4(0.f, 0.f, 0.f, 0.f);
    if (m < nrows_valid) v = *(const float4*)(src + (long)(row0 + m) * ld + k0 + kf * 4);
    dst[(kf * 4 + 0) * LST + m] = v.x;
    dst[(kf * 4 + 1) * LST + m] = v.y;
    dst[(kf * 4 + 2) * LST + m] = v.z;
    dst[(kf * 4 + 3) * LST + m] = v.w;
  }
}

// gathered-row variant: per-row element offsets in bases[64]
__device__ __forceinline__ void load_tile_gather(const float* __restrict__ src, const int* __restrict__ bases,
                                                 int k0, float* __restrict__ dst, int tid) {
#pragma unroll
  for (int i = 0; i < 8; ++i) {
    int lin = tid + 64 * i;
    int m = lin >> 3, kf = lin & 7;
    float4 v = *(const float4*)(src + bases[m] + k0 + kf * 4);
    dst[(kf * 4 + 0) * LST + m] = v.x;
    dst[(kf * 4 + 1) * LST + m] = v.y;
    dst[(kf * 4 + 2) * LST + m] = v.z;
    dst[(kf * 4 + 3) * LST + m] = v.w;
  }
}

// ---------------- setup: stable argsort(-caplens), decode_lengths, nb[t], caps_s, int outputs ----------------
__global__ __launch_bounds__(64) void setup_kernel(const int* __restrict__ caps, const int* __restrict__ caplens,
                                                   float* __restrict__ ws, float* __restrict__ out) {
  __shared__ int cl_s[64], so_s[64], dl_s[64];
  int i = threadIdx.x;
  cl_s[i] = caplens[i];
  __syncthreads();
  int cli = cl_s[i];
  int r = 0;
  for (int j = 0; j < 64; ++j) {
    int clj = cl_s[j];
    r += (clj > cli) || (clj == cli && j < i);   // stable descending rank
  }
  so_s[r] = i;
  dl_s[r] = cli - 1;
  __syncthreads();
  int* iws = (int*)ws;
  iws[WS_SORT + i] = so_s[i];
  iws[WS_DL + i] = dl_s[i];
  out[OUT_SORT + i] = (float)so_s[i];
  out[OUT_DL + i] = (float)dl_s[i];
  if (i < 49) {
    int n = 0;
    for (int b = 0; b < 64; ++b) n += (dl_s[b] > i);
    iws[WS_NB + i] = n;
  }
  for (int j = i; j < 3200; j += 64) {
    int k = j / 50, jj = j - k * 50;
    int cv = caps[so_s[k] * 50 + jj];
    iws[WS_CAPS + j] = cv;
    out[OUT_CAPS + j] = (float)cv;
  }
}

// ---------------- zero scores+weights, zero h/c/ctx, init att2 partials to {b_dec, 0...} ----------------
__global__ void zero_init_kernel(float* __restrict__ out, float* __restrict__ ws, const float* __restrict__ b_dec) {
  const float4 z = make_float4(0.f, 0.f, 0.f, 0.f);
  float4* out4 = (float4*)out;
  float4* ws4 = (float4*)ws;
  const float4* bd4 = (const float4*)b_dec;
  for (long idx = (long)blockIdx.x * 256 + threadIdx.x; idx < 8149312L; idx += (long)gridDim.x * 256) {
    if (idx < 7840000L) {                       // scores
      out4[idx] = z;
    } else if (idx < 7993664L) {                // weights
      out4[7840816L + (idx - 7840000L)] = z;
    } else if (idx < 8018240L) {                // h, c, ctx
      ws4[848L + (idx - 7993664L)] = z;
    } else {                                    // P2: ks==0 -> b_dec, else 0
      long j = idx - 8018240L;
      ws4[25424L + j] = (j < 8192L) ? bd4[j & 127] : z;
    }
  }
}

// ---------------- enc_att = feats_sorted @ W_enc^T + b_enc  (M=12544,N=512,K=512) ----------------
__global__ __launch_bounds__(64) void encatt_kernel(const float* __restrict__ image, const float* __restrict__ W_enc,
                                                    const float* __restrict__ b_enc, float* __restrict__ ws) {
  __shared__ __align__(16) float As[KC * LST];
  __shared__ __align__(16) float Bs[KC * LST];
  __shared__ int rb[64];
  int tid = threadIdx.x;
  const int* iws = (const int*)ws;
  int mt = blockIdx.x, nt = blockIdx.y;
  {
    int r = mt * 64 + tid;
    int b = r / 196;
    int p = r - b * 196;
    rb[tid] = iws[WS_SORT + b] * 100352 + p * 512;
  }
  float acc[8][8] = {};
  for (int ch = 0; ch < 16; ++ch) {
    __syncthreads();
    load_tile_gather(image, rb, ch * 32, As, tid);
    load_tile_strided(W_enc, nt * 64, 512, ch * 32, Bs, tid, 64);
    __syncthreads();
    gemm_acc(As, Bs, acc, tid & 7, tid >> 3);
  }
  int tx = tid & 7, ty = tid >> 3;
  int r0 = mt * 64 + tx * 8;
  int n0 = nt * 64 + ty * 8;
#pragma unroll
  for (int i = 0; i < 8; ++i) {
    float* cp = ws + WS_ENC + (long)(r0 + i) * 512 + n0;
    *(float4*)(cp)     = make_float4(acc[i][0] + b_enc[n0],     acc[i][1] + b_enc[n0 + 1],
                                     acc[i][2] + b_enc[n0 + 2], acc[i][3] + b_enc[n0 + 3]);
    *(float4*)(cp + 4) = make_float4(acc[i][4] + b_enc[n0 + 4], acc[i][5] + b_enc[n0 + 5],
                                     acc[i][6] + b_enc[n0 + 6], acc[i][7] + b_enc[n0 + 7]);
  }
}

// ---------------- per-step attention: att2-reduce, e, softmax, ctx, weights out (1 block / active b) ----------------
__global__ __launch_bounds__(256) void attn_kernel(float* __restrict__ ws, const float* __restrict__ image,
                                                   const float* __restrict__ W_full, const float* __restrict__ b_full,
                                                   float* __restrict__ out, int t) {
  const int* iws = (const int*)ws;
  int b = blockIdx.x;
  if (b >= iws[WS_NB + t]) return;
  __shared__ float att2_s[512], wf_s[512], e_s[200], red_s[8];
  int tid = threadIdx.x;
  for (int a = tid; a < 512; a += 256) {
    float s = 0.f;
#pragma unroll
    for (int ks = 0; ks < 16; ++ks) s += ws[WS_P2 + ks * 32768 + b * 512 + a];
    att2_s[a] = s;
    wf_s[a] = W_full[a];
  }
  __syncthreads();
  int w = tid >> 6, lane = tid & 63;
  float bf0 = b_full[0];
  for (int p = w; p < 196; p += 4) {
    const float* er = ws + WS_ENC + (long)(b * 196 + p) * 512;
    float acc = 0.f;
#pragma unroll
    for (int a8 = 0; a8 < 8; ++a8) {
      int a = (a8 << 6) + lane;
      float v = er[a] + att2_s[a];
      acc = fmaf(fmaxf(v, 0.f), wf_s[a], acc);
    }
#pragma unroll
    for (int off = 32; off; off >>= 1) acc += __shfl_down(acc, off);
    if (lane == 0) e_s[p] = acc + bf0;
  }
  __syncthreads();
  float v = (tid < 196) ? e_s[tid] : -3.4e38f;
  float mr = v;
#pragma unroll
  for (int off = 32; off; off >>= 1) mr = fmaxf(mr, __shfl_down(mr, off));
  if (lane == 0) red_s[w] = mr;
  __syncthreads();
  float mx = fmaxf(fmaxf(red_s[0], red_s[1]), fmaxf(red_s[2], red_s[3]));
  float ex = (tid < 196) ? expf(v - mx) : 0.f;
  float sr = ex;
#pragma unroll
  for (int off = 32; off; off >>= 1) sr += __shfl_down(sr, off);
  if (lane == 0) red_s[4 + w] = sr;
  __syncthreads();
  float alv = ex / (red_s[4] + red_s[5] + red_s[6] + red_s[7]);
  if (tid < 196) {
    e_s[tid] = alv;
    out[OUT_W + (long)(b * 49 + t) * 196 + tid] = alv;
  }
  __syncthreads();
  long sb = (long)iws[WS_SORT + b] * 100352;
  float a0 = 0.f, a1 = 0.f;
  for (int p = 0; p < 196; ++p) {
    float al = e_s[p];
    const float* fp = image + sb + (long)p * 512;
    a0 = fmaf(al, fp[tid], a0);
    a1 = fmaf(al, fp[tid + 256], a1);
  }
  ws[WS_CTX + b * 512 + tid] = a0;
  ws[WS_CTX + b * 512 + 256 + tid] = a1;
}

// ---------------- gates partial GEMM: [emb_t|ctx|h](64x1536) @ [W_ih;W_hh]^T, k-split 16 ----------------
__global__ __launch_bounds__(64) void gates_kernel(float* __restrict__ ws, const float* __restrict__ emb,
                                                   const float* __restrict__ W_ih, const float* __restrict__ W_hh,
                                                   int t) {
  __shared__ __align__(16) float As[KC * LST];
  __shared__ __align__(16) float Bs[KC * LST];
  __shared__ int rbe[64];
  int tid = threadIdx.x;
  int nt = blockIdx.x;   // 0..31 (64 j's each)
  int ks = blockIdx.y;   // 0..15 (96 k's each)
  int* iws = (int*)ws;
  rbe[tid] = iws[WS_CAPS + tid * 50 + t] * 512;
  float acc[8][8] = {};
  for (int ch = 0; ch < 3; ++ch) {
    int k0 = ks * 96 + ch * 32;
    __syncthreads();
    if (k0 < 512)       load_tile_gather(emb, rbe, k0, As, tid);
    else if (k0 < 1024) load_tile_strided(ws + WS_CTX, 0, 512, k0 - 512, As, tid, 64);
    else                load_tile_strided(ws + WS_H, 0, 512, k0 - 1024, As, tid, 64);
    if (k0 < 1024)      load_tile_strided(W_ih, nt * 64, 1024, k0, Bs, tid, 64);
    else                load_tile_strided(W_hh, nt * 64, 512, k0 - 1024, Bs, tid, 64);
    __syncthreads();
    gemm_acc(As, Bs, acc, tid & 7, tid >> 3);
  }
  int tx = tid & 7, ty = tid >> 3;
  float* pg = ws + WS_PG + ks * 131072;
  int j0 = nt * 64 + ty * 8;
#pragma unroll
  for (int i = 0; i < 8; ++i) {
    int b = tx * 8 + i;
    float* cp = pg + b * 2048 + j0;
    *(float4*)(cp)     = make_float4(acc[i][0], acc[i][1], acc[i][2], acc[i][3]);
    *(float4*)(cp + 4) = make_float4(acc[i][4], acc[i][5], acc[i][6], acc[i][7]);
  }
}

// ---------------- LSTM cell: reduce 16 gate partials, activations, masked h/c update ----------------
__global__ __launch_bounds__(512) void lstm_kernel(float* __restrict__ ws, const float* __restrict__ b_ih,
                                                   const float* __restrict__ b_hh, int t) {
  const int* iws = (const int*)ws;
  int b = blockIdx.x;
  if (b >= iws[WS_NB + t]) return;
  int hh = threadIdx.x;
  float gi = b_ih[hh] + b_hh[hh];
  float gf = b_ih[512 + hh] + b_hh[512 + hh];
  float gg = b_ih[1024 + hh] + b_hh[1024 + hh];
  float go = b_ih[1536 + hh] + b_hh[1536 + hh];
  const float* pg = ws + WS_PG + b * 2048;
#pragma unroll
  for (int ks = 0; ks < 16; ++ks) {
    const float* p = pg + ks * 131072;
    gi += p[hh]; gf += p[512 + hh]; gg += p[1024 + hh]; go += p[1536 + hh];
  }
  float c = ws[WS_C + b * 512 + hh];
  float cn = sigm(gf) * c + sigm(gi) * tanhf(gg);
  float hn = sigm(go) * tanhf(cn);
  ws[WS_C + b * 512 + hh] = cn;
  ws[WS_H + b * 512 + hh] = hn;
}

// ---------------- score partials (k-split 4) + next-step att2 partials (k-split 16), one launch ----------------
__global__ __launch_bounds__(64) void score_att2_kernel(float* __restrict__ ws, const float* __restrict__ W_score,
                                                        const float* __restrict__ W_dec, const float* __restrict__ b_dec,
                                                        int t) {
  __shared__ __align__(16) float As[KC * LST];
  __shared__ __align__(16) float Bs[KC * LST];
  int tid = threadIdx.x;
  int bid = blockIdx.x;
  int tx = tid & 7, ty = tid >> 3;
  float acc[8][8] = {};
  if (bid < 628) {                       // score: nt 0..156, ks 0..3 (K=128 each)
    int nt = bid >> 2, ks = bid & 3;
    int nvalid = 10000 - nt * 64; if (nvalid > 64) nvalid = 64;
    for (int ch = 0; ch < 4; ++ch) {
      int k0 = ks * 128 + ch * 32;
      __syncthreads();
      load_tile_strided(ws + WS_H, 0, 512, k0, As, tid, 64);
      load_tile_strided(W_score, nt * 64, 512, k0, Bs, tid, nvalid);
      __syncthreads();
      gemm_acc(As, Bs, acc, tx, ty);
    }
    float* ps = ws + WS_PSC + ks * 643072;
    int n0 = nt * 64 + ty * 8;
#pragma unroll
    for (int i = 0; i < 8; ++i) {
      int b = tx * 8 + i;
      float* cp = ps + b * 10048 + n0;
      *(float4*)(cp)     = make_float4(acc[i][0], acc[i][1], acc[i][2], acc[i][3]);
      *(float4*)(cp + 4) = make_float4(acc[i][4], acc[i][5], acc[i][6], acc[i][7]);
    }
  } else {                               // att2 for step t+1: nt 0..7, ks 0..15 (K=32 each)
    int u = bid - 628;
    int nt = u >> 4, ks = u & 15;
    int k0 = ks * 32;
    __syncthreads();
    load_tile_strided(ws + WS_H, 0, 512, k0, As, tid, 64);
    load_tile_strided(W_dec, nt * 64, 512, k0, Bs, tid, 64);
    __syncthreads();
    gemm_acc(As, Bs, acc, tx, ty);
    float* p2 = ws + WS_P2 + ks * 32768;
    int n0 = nt * 64 + ty * 8;
#pragma unroll
    for (int i = 0; i < 8; ++i) {
      int b = tx * 8 + i;
      float bd0 = (ks == 0) ? b_dec[n0]     : 0.f;
      float bd1 = (ks == 0) ? b_dec[n0 + 1] : 0.f;
      float bd2 = (ks == 0) ? b_dec[n0 + 2] : 0.f;
      float bd3 = (ks == 0) ? b_dec[n0 + 3] : 0.f;
      float bd4 = (ks == 0) ? b_dec[n0 + 4] : 0.f;
      float bd5 = (ks == 0) ? b_dec[n0 + 5] : 0.f;
      float bd6 = (ks == 0) ? b_dec[n0 + 6] : 0.f;
      float bd7 = (ks == 0) ? b_dec[n0 + 7] : 0.f;
      float* cp = p2 + b * 512 + n0;
      *(float4*)(cp)     = make_float4(acc[i][0] + bd0, acc[i][1] + bd1, acc[i][2] + bd2, acc[i][3] + bd3);
      *(float4*)(cp + 4) = make_float4(acc[i][4] + bd4, acc[i][5] + bd5, acc[i][6] + bd6, acc[i][7] + bd7);
    }
  }
}

// ---------------- score reduce + bias + masked write ----------------
__global__ __launch_bounds__(256) void score_red_kernel(const float* __restrict__ ws, const float* __restrict__ b_score,
                                                        float* __restrict__ out, int t) {
  const int* iws = (const int*)ws;
  int gid = blockIdx.x * 256 + threadIdx.x;
  if (gid >= 640000) return;
  int b = gid / 10000, vv = gid - b * 10000;
  if (b >= iws[WS_NB + t]) return;
  float s = b_score[vv];
#pragma unroll
  for (int ks = 0; ks < 4; ++ks) s += ws[WS_PSC + ks * 643072 + b * 10048 + vv];
  out[(long)b * 490000 + t * 10000 + vv] = s;
}

// ---------------- launch ----------------
extern "C" void kernel_launch(void* const* d_in, const int* in_sizes, int n_in,
                              void* d_out, int out_size, void* d_ws, size_t ws_size,
                              hipStream_t stream) {
  const float* image   = (const float*)d_in[0];
  const int*   caps    = (const int*)d_in[1];
  const int*   caplens = (const int*)d_in[2];
  const float* emb     = (const float*)d_in[3];
  const float* W_ih    = (const float*)d_in[4];
  const float* W_hh    = (const float*)d_in[5];
  const float* b_ih    = (const float*)d_in[6];
  const float* b_hh    = (const float*)d_in[7];
  const float* W_enc   = (const float*)d_in[8];
  const float* b_enc   = (const float*)d_in[9];
  const float* W_dec   = (const float*)d_in[10];
  const float* b_dec   = (const float*)d_in[11];
  const float* W_full  = (const float*)d_in[12];
  const float* b_full  = (const float*)d_in[13];
  const float* W_score = (const float*)d_in[14];
  const float* b_score = (const float*)d_in[15];
  float* out = (float*)d_out;
  float* ws  = (float*)d_ws;

  setup_kernel<<<1, 64, 0, stream>>>(caps, caplens, ws, out);
  zero_init_kernel<<<2048, 256, 0, stream>>>(out, ws, b_dec);
  encatt_kernel<<<dim3(196, 8), 64, 0, stream>>>(image, W_enc, b_enc, ws);
  for (int t = 0; t < 49; ++t) {
    attn_kernel<<<64, 256, 0, stream>>>(ws, image, W_full, b_full, out, t);
    gates_kernel<<<dim3(32, 16), 64, 0, stream>>>(ws, emb, W_ih, W_hh, t);
    lstm_kernel<<<64, 512, 0, stream>>>(ws, b_ih, b_hh, t);
    score_att2_kernel<<<756, 64, 0, stream>>>(ws, W_score, W_dec, b_dec, t);
    score_red_kernel<<<2500, 256, 0, stream>>>(ws, b_score, out, t);
  }
}

// Round 2
// 2879.598 us; speedup vs baseline: 2.0155x; 2.0155x over previous
//
#include <hip/hip_runtime.h>
#include <math.h>

// ---------------- problem constants ----------------
// B=64, P=196, H=E=A=512, V=10000, T=49, gates=2048, Kx=1536

// ---------------- ws layout (element offsets) ----------------
#define WS_SORT   0             // int[64]
#define WS_DL     64            // int[64]
#define WS_NB     128           // int[64]: nb[0..48], [49]=R
#define WS_ROWOFF 192           // int[64] (50 used)
#define WS_CAPS   256           // int[64*50]
#define WS_RMAP   3456          // int[3136]: t*64+b per compact row
#define WS_H      6592          // float[64*512]
#define WS_C      39360         // float[64*512]
#define WS_ATT2   72128         // float[64*512] (includes b_dec)
#define WS_E      104896        // float[64*200] exp(e) values
#define WS_Z      117696        // float[4][64] expsum partials
#define WS_CTXP   117952        // float[4][64][512] unnormalized ctx partials
#define WS_PG     249024        // float[16][64][2048] gates k-split partials
#define WS_HALL   2346176       // float[3136*512] compact h_new rows
#define WS_ENC    3951808       // float[12544*512] enc_att
// end = 10,374,336 floats = 41.5 MB

// ---------------- out layout (floats) ----------------
#define OUT_SCORES 0            // (64,49,10000)
#define OUT_CAPS   31360000     // (64,50)
#define OUT_DL     31363200     // (64,)
#define OUT_W      31363264     // (64,49,196)
#define OUT_SORT   31977920     // (64,)

#define KC  32
#define LST 68

__device__ __forceinline__ float sigm(float x) { return 1.f / (1.f + expf(-x)); }

// ---------------- fp32 GEMM core: 64 threads, 64x64 tile, 8x8 micro ----------------
__device__ __forceinline__ void gemm_acc(const float* __restrict__ As, const float* __restrict__ Bs,
                                         float acc[8][8], int tx, int ty) {
#pragma unroll 8
  for (int kk = 0; kk < KC; ++kk) {
    const float4* ar = (const float4*)(As + kk * LST + tx * 8);
    const float4* br = (const float4*)(Bs + kk * LST + ty * 8);
    float4 a0 = ar[0], a1 = ar[1];
    float4 b0 = br[0], b1 = br[1];
    float av[8] = {a0.x, a0.y, a0.z, a0.w, a1.x, a1.y, a1.z, a1.w};
    float bv[8] = {b0.x, b0.y, b0.z, b0.w, b1.x, b1.y, b1.z, b1.w};
#pragma unroll
    for (int i = 0; i < 8; ++i)
#pragma unroll
      for (int j = 0; j < 8; ++j)
        acc[i][j] = fmaf(av[i], bv[j], acc[i][j]);
  }
}

__device__ __forceinline__ void load_tile_strided(const float* __restrict__ src, int row0, int ld, int k0,
                                                  float* __restrict__ dst, int tid, int nrows_valid) {
#pragma unroll
  for (int i = 0; i < 8; ++i) {
    int lin = tid + 64 * i;
    int m = lin >> 3, kf = lin & 7;
    float4 v = make_float4(0.f, 0.f, 0.f, 0.f);
    if (m < nrows_valid) v = *(const float4*)(src + (long)(row0 + m) * ld + k0 + kf * 4);
    dst[(kf * 4 + 0) * LST + m] = v.x;
    dst[(kf * 4 + 1) * LST + m] = v.y;
    dst[(kf * 4 + 2) * LST + m] = v.z;
    dst[(kf * 4 + 3) * LST + m] = v.w;
  }
}

__device__ __forceinline__ void load_tile_gather(const float* __restrict__ src, const int* __restrict__ bases,
                                                 int k0, float* __restrict__ dst, int tid) {
#pragma unroll
  for (int i = 0; i < 8; ++i) {
    int lin = tid + 64 * i;
    int m = lin >> 3, kf = lin & 7;
    float4 v = *(const float4*)(src + bases[m] + k0 + kf * 4);
    dst[(kf * 4 + 0) * LST + m] = v.x;
    dst[(kf * 4 + 1) * LST + m] = v.y;
    dst[(kf * 4 + 2) * LST + m] = v.z;
    dst[(kf * 4 + 3) * LST + m] = v.w;
  }
}

// ---------------- setup ----------------
__global__ __launch_bounds__(64) void setup_kernel(const int* __restrict__ caps, const int* __restrict__ caplens,
                                                   float* __restrict__ ws, float* __restrict__ out) {
  __shared__ int cl_s[64], so_s[64], dl_s[64], nb_s[49], ro_s[50];
  int i = threadIdx.x;
  cl_s[i] = caplens[i];
  __syncthreads();
  int cli = cl_s[i];
  int r = 0;
  for (int j = 0; j < 64; ++j) {
    int clj = cl_s[j];
    r += (clj > cli) || (clj == cli && j < i);   // stable descending
  }
  so_s[r] = i;
  dl_s[r] = cli - 1;
  __syncthreads();
  int* iws = (int*)ws;
  iws[WS_SORT + i] = so_s[i];
  iws[WS_DL + i] = dl_s[i];
  out[OUT_SORT + i] = (float)so_s[i];
  out[OUT_DL + i] = (float)dl_s[i];
  if (i < 49) {
    int n = 0;
    for (int b = 0; b < 64; ++b) n += (dl_s[b] > i);
    iws[WS_NB + i] = n;
    nb_s[i] = n;
  }
  __syncthreads();
  if (i == 0) {
    int acc = 0;
    for (int t = 0; t < 49; ++t) { ro_s[t] = acc; acc += nb_s[t]; }
    ro_s[49] = acc;
    iws[WS_NB + 49] = acc;
  }
  __syncthreads();
  if (i < 50) iws[WS_ROWOFF + i] = ro_s[i];
  int R = ro_s[49];
  for (int rr = i; rr < 3136; rr += 64) {
    int val = 0;
    if (rr < R) {
      int t = 0;
      while (t < 48 && ro_s[t + 1] <= rr) ++t;
      val = t * 64 + (rr - ro_s[t]);
    }
    iws[WS_RMAP + rr] = val;
  }
  for (int j = i; j < 3200; j += 64) {
    int k = j / 50, jj = j - k * 50;
    int cv = caps[so_s[k] * 50 + jj];
    iws[WS_CAPS + j] = cv;
    out[OUT_CAPS + j] = (float)cv;
  }
}

// ---------------- zero scores+weights+h/c, att2 = b_dec ----------------
__global__ void zero_init_kernel(float* __restrict__ out, float* __restrict__ ws, const float* __restrict__ b_dec) {
  const float4 z = make_float4(0.f, 0.f, 0.f, 0.f);
  float4* out4 = (float4*)out;
  float4* ws4 = (float4*)ws;
  const float4* bd4 = (const float4*)b_dec;
  for (long idx = (long)blockIdx.x * 256 + threadIdx.x; idx < 8018240L; idx += (long)gridDim.x * 256) {
    if (idx < 7840000L) {
      out4[idx] = z;                                   // scores
    } else if (idx < 7993664L) {
      out4[7840816L + (idx - 7840000L)] = z;           // weights
    } else if (idx < 8010048L) {
      ws4[1648L + (idx - 7993664L)] = z;               // h, c
    } else {
      long j = idx - 8010048L;
      ws4[18032L + j] = bd4[j & 127];                  // att2 = b_dec
    }
  }
}

// ---------------- enc_att = feats_sorted @ W_enc^T + b_enc ----------------
__global__ __launch_bounds__(64) void encatt_kernel(const float* __restrict__ image, const float* __restrict__ W_enc,
                                                    const float* __restrict__ b_enc, float* __restrict__ ws) {
  __shared__ __align__(16) float As[KC * LST];
  __shared__ __align__(16) float Bs[KC * LST];
  __shared__ int rb[64];
  int tid = threadIdx.x;
  const int* iws = (const int*)ws;
  int mt = blockIdx.x, nt = blockIdx.y;
  {
    int r = mt * 64 + tid;
    int b = r / 196;
    int p = r - b * 196;
    rb[tid] = iws[WS_SORT + b] * 100352 + p * 512;
  }
  float acc[8][8] = {};
  for (int ch = 0; ch < 16; ++ch) {
    __syncthreads();
    load_tile_gather(image, rb, ch * 32, As, tid);
    load_tile_strided(W_enc, nt * 64, 512, ch * 32, Bs, tid, 64);
    __syncthreads();
    gemm_acc(As, Bs, acc, tid & 7, tid >> 3);
  }
  int tx = tid & 7, ty = tid >> 3;
  int r0 = mt * 64 + tx * 8;
  int n0 = nt * 64 + ty * 8;
#pragma unroll
  for (int i = 0; i < 8; ++i) {
    float* cp = ws + WS_ENC + (long)(r0 + i) * 512 + n0;
    *(float4*)(cp)     = make_float4(acc[i][0] + b_enc[n0],     acc[i][1] + b_enc[n0 + 1],
                                     acc[i][2] + b_enc[n0 + 2], acc[i][3] + b_enc[n0 + 3]);
    *(float4*)(cp + 4) = make_float4(acc[i][4] + b_enc[n0 + 4], acc[i][5] + b_enc[n0 + 5],
                                     acc[i][6] + b_enc[n0 + 6], acc[i][7] + b_enc[n0 + 7]);
  }
}

// ---------------- K1: e = relu(enc+att2)@W_full, exp, Z partial, ctx partial ----------------
__global__ __launch_bounds__(256) void ectx_kernel(float* __restrict__ ws, const float* __restrict__ image,
                                                   const float* __restrict__ W_full, const float* __restrict__ b_full,
                                                   int t) {
  const int* iws = (const int*)ws;
  int b = blockIdx.x;
  if (b >= iws[WS_NB + t]) return;
  int pg = blockIdx.y;
  __shared__ float att2_s[512], wf_s[512], e_s[52];
  int tid = threadIdx.x;
  for (int a = tid; a < 512; a += 256) {
    att2_s[a] = ws[WS_ATT2 + b * 512 + a];
    wf_s[a] = W_full[a];
  }
  __syncthreads();
  int w = tid >> 6, lane = tid & 63;
  float bf0 = b_full[0];
  for (int idx = w; idx < 49; idx += 4) {
    int p = pg * 49 + idx;
    const float* er = ws + WS_ENC + (long)(b * 196 + p) * 512;
    float acc = 0.f;
#pragma unroll
    for (int a8 = 0; a8 < 8; ++a8) {
      int a = (a8 << 6) + lane;
      float v = er[a] + att2_s[a];
      acc = fmaf(fmaxf(v, 0.f), wf_s[a], acc);
    }
#pragma unroll
    for (int off = 32; off; off >>= 1) acc += __shfl_down(acc, off);
    if (lane == 0) e_s[idx] = expf(acc + bf0);   // store exp(e); no max-sub (|e|<~2)
  }
  __syncthreads();
  if (tid < 49) ws[WS_E + b * 200 + pg * 49 + tid] = e_s[tid];
  if (tid == 0) {
    float zz = 0.f;
    for (int j = 0; j < 49; ++j) zz += e_s[j];
    ws[WS_Z + pg * 64 + b] = zz;
  }
  long sb = (long)iws[WS_SORT + b] * 100352;
  float a0 = 0.f, a1 = 0.f;
  for (int j = 0; j < 49; ++j) {
    float al = e_s[j];
    const float* fp = image + sb + (long)(pg * 49 + j) * 512;
    a0 = fmaf(al, fp[tid], a0);
    a1 = fmaf(al, fp[tid + 256], a1);
  }
  ws[WS_CTXP + pg * 32768 + b * 512 + tid] = a0;
  ws[WS_CTXP + pg * 32768 + b * 512 + 256 + tid] = a1;
}

// ---------------- K2: gates partial GEMM (ctx normalized on the fly) ----------------
__global__ __launch_bounds__(64) void gates_kernel(float* __restrict__ ws, const float* __restrict__ emb,
                                                   const float* __restrict__ W_ih, const float* __restrict__ W_hh,
                                                   int t) {
  __shared__ __align__(16) float As[KC * LST];
  __shared__ __align__(16) float Bs[KC * LST];
  __shared__ int rbe[64];
  __shared__ float rcpz_s[64];
  int tid = threadIdx.x;
  int nt = blockIdx.x;   // 0..31
  int ks = blockIdx.y;   // 0..15 (96 k's each)
  int* iws = (int*)ws;
  rbe[tid] = iws[WS_CAPS + tid * 50 + t] * 512;
  {
    float zz = ws[WS_Z + tid] + ws[WS_Z + 64 + tid] + ws[WS_Z + 128 + tid] + ws[WS_Z + 192 + tid];
    rcpz_s[tid] = 1.f / zz;
  }
  float acc[8][8] = {};
  for (int ch = 0; ch < 3; ++ch) {
    int k0 = ks * 96 + ch * 32;
    __syncthreads();
    if (k0 < 512) {
      load_tile_gather(emb, rbe, k0, As, tid);
    } else if (k0 < 1024) {
      int kc = k0 - 512;
#pragma unroll
      for (int i = 0; i < 8; ++i) {
        int lin = tid + 64 * i;
        int m = lin >> 3, kf = lin & 7;
        const float* base = ws + WS_CTXP + m * 512 + kc + kf * 4;
        float4 v0 = *(const float4*)(base);
        float4 v1 = *(const float4*)(base + 32768);
        float4 v2 = *(const float4*)(base + 65536);
        float4 v3 = *(const float4*)(base + 98304);
        float rz = rcpz_s[m];
        As[(kf * 4 + 0) * LST + m] = (v0.x + v1.x + v2.x + v3.x) * rz;
        As[(kf * 4 + 1) * LST + m] = (v0.y + v1.y + v2.y + v3.y) * rz;
        As[(kf * 4 + 2) * LST + m] = (v0.z + v1.z + v2.z + v3.z) * rz;
        As[(kf * 4 + 3) * LST + m] = (v0.w + v1.w + v2.w + v3.w) * rz;
      }
    } else {
      load_tile_strided(ws + WS_H, 0, 512, k0 - 1024, As, tid, 64);
    }
    if (k0 < 1024) load_tile_strided(W_ih, nt * 64, 1024, k0, Bs, tid, 64);
    else           load_tile_strided(W_hh, nt * 64, 512, k0 - 1024, Bs, tid, 64);
    __syncthreads();
    gemm_acc(As, Bs, acc, tid & 7, tid >> 3);
  }
  int tx = tid & 7, ty = tid >> 3;
  float* pg = ws + WS_PG + ks * 131072;
  int j0 = nt * 64 + ty * 8;
#pragma unroll
  for (int i = 0; i < 8; ++i) {
    int b = tx * 8 + i;
    float* cp = pg + b * 2048 + j0;
    *(float4*)(cp)     = make_float4(acc[i][0], acc[i][1], acc[i][2], acc[i][3]);
    *(float4*)(cp + 4) = make_float4(acc[i][4], acc[i][5], acc[i][6], acc[i][7]);
  }
}

// ---------------- K3: reduce gates, LSTM cell, h_all store, weights out, att2(t+1) ----------------
__global__ __launch_bounds__(512) void lstm_att2_kernel(float* __restrict__ ws, const float* __restrict__ b_ih,
                                                        const float* __restrict__ b_hh, const float* __restrict__ W_dec,
                                                        const float* __restrict__ b_dec, float* __restrict__ out, int t) {
  const int* iws = (const int*)ws;
  int b = blockIdx.x;
  int as = blockIdx.y;          // a-split 0..3
  int hh = threadIdx.x;
  int nb = iws[WS_NB + t];
  __shared__ float h_s[512], red[512];
  float gi = b_ih[hh] + b_hh[hh];
  float gf = b_ih[512 + hh] + b_hh[512 + hh];
  float gg = b_ih[1024 + hh] + b_hh[1024 + hh];
  float go = b_ih[1536 + hh] + b_hh[1536 + hh];
  const float* pgp = ws + WS_PG + b * 2048;
#pragma unroll
  for (int ks = 0; ks < 16; ++ks) {
    const float* p = pgp + ks * 131072;
    gi += p[hh]; gf += p[512 + hh]; gg += p[1024 + hh]; go += p[1536 + hh];
  }
  float c = ws[WS_C + b * 512 + hh];
  float cn = sigm(gf) * c + sigm(gi) * tanhf(gg);
  float hn = sigm(go) * tanhf(cn);
  h_s[hh] = hn;
  if (b < nb) {
    if (as == 0) {
      ws[WS_C + b * 512 + hh] = cn;
      ws[WS_H + b * 512 + hh] = hn;
      ws[WS_HALL + (long)(iws[WS_ROWOFF + t] + b) * 512 + hh] = hn;
    }
    if (hh < 49) {   // weights out for this quarter
      float zz = ws[WS_Z + b] + ws[WS_Z + 64 + b] + ws[WS_Z + 128 + b] + ws[WS_Z + 192 + b];
      int p = as * 49 + hh;
      out[OUT_W + (long)(b * 49 + t) * 196 + p] = ws[WS_E + b * 200 + p] / zz;
    }
  }
  __syncthreads();
  // att2(t+1) for a-range [as*128, as*128+128)
  int a = as * 128 + (hh >> 2);
  int part = hh & 3;
  const float* wd = W_dec + (long)a * 512 + part * 128;
  const float* hp = h_s + part * 128;
  float s = 0.f;
#pragma unroll 8
  for (int j = 0; j < 32; ++j) {
    float4 wv = *(const float4*)(wd + 4 * j);
    s = fmaf(hp[4 * j], wv.x, s);
    s = fmaf(hp[4 * j + 1], wv.y, s);
    s = fmaf(hp[4 * j + 2], wv.z, s);
    s = fmaf(hp[4 * j + 3], wv.w, s);
  }
  red[hh] = s;
  __syncthreads();
  if (part == 0) {
    float v = red[hh] + red[hh + 1] + red[hh + 2] + red[hh + 3] + b_dec[a];
    ws[WS_ATT2 + b * 512 + a] = v;
  }
}

// ---------------- post-loop: scores = H_all @ W_score^T + b_score (compact rows) ----------------
__global__ __launch_bounds__(64) void score_kernel(const float* __restrict__ ws, const float* __restrict__ W_score,
                                                   const float* __restrict__ b_score, float* __restrict__ out) {
  __shared__ __align__(16) float As[KC * LST];
  __shared__ __align__(16) float Bs[KC * LST];
  const int* iws = (const int*)ws;
  int mt = blockIdx.x, nt = blockIdx.y;
  int R = iws[WS_NB + 49];
  if (mt * 64 >= R) return;
  int tid = threadIdx.x;
  int mvalid = R - mt * 64; if (mvalid > 64) mvalid = 64;
  int nvalid = 10000 - nt * 64; if (nvalid > 64) nvalid = 64;
  float acc[8][8] = {};
  for (int ch = 0; ch < 16; ++ch) {
    __syncthreads();
    load_tile_strided(ws + WS_HALL, mt * 64, 512, ch * 32, As, tid, mvalid);
    load_tile_strided(W_score, nt * 64, 512, ch * 32, Bs, tid, nvalid);
    __syncthreads();
    gemm_acc(As, Bs, acc, tid & 7, tid >> 3);
  }
  int tx = tid & 7, ty = tid >> 3;
  int n0 = nt * 64 + ty * 8;
#pragma unroll
  for (int i = 0; i < 8; ++i) {
    int r = mt * 64 + tx * 8 + i;
    if (r >= R) continue;
    int tb = iws[WS_RMAP + r];
    int bb = tb & 63, tt = tb >> 6;
    float* cp = out + (long)bb * 490000 + tt * 10000 + n0;
    if (n0 + 4 <= 10000)
      *(float4*)(cp)     = make_float4(acc[i][0] + b_score[n0],     acc[i][1] + b_score[n0 + 1],
                                       acc[i][2] + b_score[n0 + 2], acc[i][3] + b_score[n0 + 3]);
    if (n0 + 8 <= 10000)
      *(float4*)(cp + 4) = make_float4(acc[i][4] + b_score[n0 + 4], acc[i][5] + b_score[n0 + 5],
                                       acc[i][6] + b_score[n0 + 6], acc[i][7] + b_score[n0 + 7]);
  }
}

// ---------------- launch ----------------
extern "C" void kernel_launch(void* const* d_in, const int* in_sizes, int n_in,
                              void* d_out, int out_size, void* d_ws, size_t ws_size,
                              hipStream_t stream) {
  const float* image   = (const float*)d_in[0];
  const int*   caps    = (const int*)d_in[1];
  const int*   caplens = (const int*)d_in[2];
  const float* emb     = (const float*)d_in[3];
  const float* W_ih    = (const float*)d_in[4];
  const float* W_hh    = (const float*)d_in[5];
  const float* b_ih    = (const float*)d_in[6];
  const float* b_hh    = (const float*)d_in[7];
  const float* W_enc   = (const float*)d_in[8];
  const float* b_enc   = (const float*)d_in[9];
  const float* W_dec   = (const float*)d_in[10];
  const float* b_dec   = (const float*)d_in[11];
  const float* W_full  = (const float*)d_in[12];
  const float* b_full  = (const float*)d_in[13];
  const float* W_score = (const float*)d_in[14];
  const float* b_score = (const float*)d_in[15];
  float* out = (float*)d_out;
  float* ws  = (float*)d_ws;

  setup_kernel<<<1, 64, 0, stream>>>(caps, caplens, ws, out);
  zero_init_kernel<<<2048, 256, 0, stream>>>(out, ws, b_dec);
  encatt_kernel<<<dim3(196, 8), 64, 0, stream>>>(image, W_enc, b_enc, ws);
  for (int t = 0; t < 49; ++t) {
    ectx_kernel<<<dim3(64, 4), 256, 0, stream>>>(ws, image, W_full, b_full, t);
    gates_kernel<<<dim3(32, 16), 64, 0, stream>>>(ws, emb, W_ih, W_hh, t);
    lstm_att2_kernel<<<dim3(64, 4), 512, 0, stream>>>(ws, b_ih, b_hh, W_dec, b_dec, out, t);
  }
  score_kernel<<<dim3(49, 157), 64, 0, stream>>>(ws, W_score, b_score, out);
}